// Round 7
// baseline (63.345 us; speedup 1.0000x reference)
//
#include <hip/hip_runtime.h>
#include <hip/hip_bf16.h>

typedef __attribute__((ext_vector_type(8))) short bf16x8;
typedef __attribute__((ext_vector_type(4))) float f32x4;

#define CC 128
#define KK 128
#define HH 56
#define WW 56
#define HW (HH * WW)

#define XP_OFF (512 * 1024)  // ws: wt6 at 0 (288KB), xp at 512KB (15.2MB)

__device__ __forceinline__ unsigned short f2bf(float f) {
  unsigned int u = __builtin_bit_cast(unsigned int, f);
  u += 0x7FFFu + ((u >> 16) & 1u);
  return (unsigned short)(u >> 16);
}

__device__ __forceinline__ void gload_lds16(const void* g, void* l) {
  __builtin_amdgcn_global_load_lds((__attribute__((address_space(1))) void*)g,
                                   (__attribute__((address_space(3))) void*)l,
                                   16, 0, 0);
}

// K0: x fp32 NCHW -> xp bf16 [n*16+o][58h][64w][8ci], zero-padded halo
// (h idx 0,57 zero; w idx 0 and 57..63 zero). 950272 cells of 16B.
__global__ void prepack_kernel(const float* __restrict__ x,
                               unsigned short* __restrict__ xp) {
  int idx = blockIdx.x * 256 + threadIdx.x;  // 950272 exact
  int w = idx & 63;
  int r = idx >> 6;
  int h = r % 58;
  int t = r / 58;  // n*16 + o
  bool ok = (w >= 1) && (w <= 56) && (h >= 1) && (h <= 56);
  const float* src = x + (size_t)t * 8 * HW + (h - 1) * WW + (w - 1);
  unsigned short o[8];
#pragma unroll
  for (int ci = 0; ci < 8; ++ci) {
    float v = ok ? src[ci * HW] : 0.f;
    o[ci] = f2bf(v);
  }
  *(bf16x8*)(xp + (size_t)idx * 8) = *(bf16x8*)o;
}

// K1: kernel (K,C,3,3) f32 -> wt6 bf16 A-fragment order:
// e = (((((rs*2+cp)*2+ks)*2+kp)*4+f)*64 + l)*8 + j
// k = kp*64+f*16+(l&15) ; c = cp*64+ks*32+(l>>4)*8+j
__global__ void wtrans_kernel(const float* __restrict__ kin,
                              unsigned short* __restrict__ wt6) {
  int e = blockIdx.x * 256 + threadIdx.x;  // 147456 exact
  int j = e & 7;
  int l = (e >> 3) & 63;
  int f = (e >> 9) & 3;
  int kp = (e >> 11) & 1;
  int ks = (e >> 12) & 1;
  int cp = (e >> 13) & 1;
  int rs = e >> 14;  // 0..8
  int k = kp * 64 + f * 16 + (l & 15);
  int c = cp * 64 + ks * 32 + (l >> 4) * 8 + j;
  wt6[e] = f2bf(kin[(k * CC + c) * 9 + rs]);
}

// K2: 3x3 conv, implicit GEMM, mfma_f32_16x16x32_bf16.
// Grid (56 = 14bh x 4bw, 16n), 256 thr (4 waves). Block tile: 128k x 4h x 16w
// (bw=3: only w 48..55 valid -> store-masked). Wave (kp, cp): 64k x 64sp over
// channel-half cp (K=576). NO barriers in the K-loop; x staged once in the
// prologue via global_load_lds (pre-swizzled source); A from global (L2-hot)
// with depth-1 prefetch; cp-halves reduced through LDS at the end.
__global__ __launch_bounds__(256, 3) void conv_kernel(
    const unsigned short* __restrict__ xp, const unsigned short* __restrict__ wt6,
    float* __restrict__ out) {
  __shared__ __align__(16) unsigned char xs[32768];  // x: 27648B; redn: 32KB

  const int tid = threadIdx.x;
  const int lane = tid & 63;
  const int wv = tid >> 6;    // 0..3
  const int bx = blockIdx.x;  // 0..55
  const int bh = bx >> 2;
  const int bw = bx & 3;
  const int n = blockIdx.y;
  const int r0 = bh * 4;
  const int w0 = bw * 16;

  const int cidx = lane & 15;  // spatial col within fragment (w offset)
  const int q = lane >> 4;     // 0..3

  const int kp = wv >> 1;
  const int cp = wv & 1;
  const int obase = cp * 8 + q;

  // ---- prologue: stage x cells (row6 x col18 x slot16) via glds ----
  // cell L = i*64+lane ; slot s=L&15, col=(L>>4)%18, row=(L>>4)/18 ;
  // oct o=(s-col)&15  (additive swizzle via pre-swizzled global source).
#pragma unroll
  for (int t = 0; t < 7; ++t) {
    const int i = wv + 4 * t;
    if (i < 27) {
      const int L = i * 64 + lane;
      const int s = L & 15;
      const int cell = L >> 4;
      const int col = cell % 18;
      const int row = cell / 18;
      const int o = (s - col) & 15;
      const unsigned short* src =
          xp + ((((size_t)(n * 16 + o)) * 58 + (r0 + row)) * 64 + (w0 + col)) * 8;
      gload_lds16(src, xs + i * 1024);
    }
  }
  asm volatile("s_waitcnt vmcnt(0)" ::: "memory");
  __syncthreads();

  f32x4 acc[4][4] = {};  // [f][fi]
  bf16x8 Ar[2][4], Br[2][4];

  auto ldA = [&](int rs, int ks, bf16x8* D) {
    const unsigned short* base =
        wt6 + (((((rs * 2 + cp) * 2 + ks) * 2 + kp) * 4) << 9) + lane * 8;
#pragma unroll
    for (int f = 0; f < 4; ++f) D[f] = *(const bf16x8*)(base + f * 512);
  };
  auto ldB = [&](int fr, int fs, int ks, bf16x8* D) {
    const int colp = cidx + fs;
    const int slot = (obase + ks * 4 + colp) & 15;
#pragma unroll
    for (int fi = 0; fi < 4; ++fi)
      D[fi] = *(const bf16x8*)(xs + ((fi + fr) * 18 + colp) * 256 + slot * 16);
  };

  ldA(0, 0, Ar[0]);
  ldB(0, 0, 0, Br[0]);

#pragma unroll
  for (int u = 0; u < 18; ++u) {
    const int rsn = (u + 1) >> 1;
    const int ksn = (u + 1) & 1;
    if (u < 17) {
      ldA(rsn, ksn, Ar[(u + 1) & 1]);
      ldB(rsn / 3, rsn % 3, ksn, Br[(u + 1) & 1]);
    }
#pragma unroll
    for (int f = 0; f < 4; ++f)
#pragma unroll
      for (int fi = 0; fi < 4; ++fi)
        acc[f][fi] = __builtin_amdgcn_mfma_f32_16x16x32_bf16(
            Ar[u & 1][f], Br[u & 1][fi], acc[f][fi], 0, 0, 0);
  }

  // ---- reduce cp halves through LDS, then store ----
  __syncthreads();  // everyone done reading xs
  if (cp == 1) {
#pragma unroll
    for (int f = 0; f < 4; ++f)
#pragma unroll
      for (int fi = 0; fi < 4; ++fi)
        *(f32x4*)(xs + kp * 16384 + ((f * 4 + fi) * 64 + lane) * 16) = acc[f][fi];
  }
  __syncthreads();
  if (cp == 0) {
    const bool wok = (bw < 3) || (cidx < 8);
#pragma unroll
    for (int f = 0; f < 4; ++f) {
#pragma unroll
      for (int fi = 0; fi < 4; ++fi) {
        f32x4 other = *(const f32x4*)(xs + kp * 16384 + ((f * 4 + fi) * 64 + lane) * 16);
        f32x4 r = acc[f][fi] + other;
        if (wok) {
          const int k = kp * 64 + f * 16 + q * 4;
          float* op = out + (((size_t)n * KK + k) * HH + (r0 + fi)) * WW + w0 + cidx;
          op[0 * HW] = r[0];
          op[1 * HW] = r[1];
          op[2 * HW] = r[2];
          op[3 * HW] = r[3];
        }
      }
    }
  }
}

extern "C" void kernel_launch(void* const* d_in, const int* in_sizes, int n_in,
                              void* d_out, int out_size, void* d_ws, size_t ws_size,
                              hipStream_t stream) {
  const float* x = (const float*)d_in[0];
  const float* kin = (const float*)d_in[1];
  float* out = (float*)d_out;
  unsigned short* wt6 = (unsigned short*)d_ws;
  unsigned short* xp = (unsigned short*)((char*)d_ws + XP_OFF);

  hipLaunchKernelGGL(prepack_kernel, dim3(3712), dim3(256), 0, stream, x, xp);
  hipLaunchKernelGGL(wtrans_kernel, dim3(576), dim3(256), 0, stream, kin, wt6);
  hipLaunchKernelGGL(conv_kernel, dim3(56, 16), dim3(256), 0, stream, xp, wt6, out);
}

// Round 8
// 50.421 us; speedup vs baseline: 1.2563x; 1.2563x over previous
//
#include <hip/hip_runtime.h>
#include <hip/hip_bf16.h>

typedef __attribute__((ext_vector_type(8))) short bf16x8;
typedef __attribute__((ext_vector_type(4))) float f32x4;

#define CC 128
#define KK 128
#define HH 56
#define WW 56
#define HW (HH * WW)

#define XP_OFF (512 * 1024)  // ws: wt at 0 (288KB), xp at 512KB (15.7MB)

__device__ __forceinline__ unsigned short f2bf(float f) {
  unsigned int u = __builtin_bit_cast(unsigned int, f);
  u += 0x7FFFu + ((u >> 16) & 1u);
  return (unsigned short)(u >> 16);
}

__device__ __forceinline__ void gload_lds16(const void* g, void* l) {
  __builtin_amdgcn_global_load_lds((__attribute__((address_space(1))) void*)g,
                                   (__attribute__((address_space(3))) void*)l,
                                   16, 0, 0);
}

// K0: x fp32 NCHW -> xp bf16 [n][hr 58][wc 66][c 128], zero-padded halo.
// xp row hr = x row hr-1; col wc = x col wc-1 (wc 57..65 zero: covers fs-shift
// reads so the conv K-loop needs NO bounds checks).
__global__ void prepack_kernel(const float* __restrict__ x,
                               unsigned short* __restrict__ xp) {
  int u = blockIdx.x * 256 + threadIdx.x;  // 979968 exact
  int coct = u & 15;
  int cell = u >> 4;       // (n*58 + hr)*66 + wc
  int wc = cell % 66;
  int rest = cell / 66;
  int hr = rest % 58;
  int n = rest / 58;
  bool ok = (hr >= 1) && (hr <= 56) && (wc >= 1) && (wc <= 56);
  const float* src =
      x + ((size_t)(n * CC + coct * 8) * HH + (hr - 1)) * WW + (wc - 1);
  unsigned short o[8];
#pragma unroll
  for (int ci = 0; ci < 8; ++ci) {
    float v = ok ? src[(size_t)ci * HW] : 0.f;
    o[ci] = f2bf(v);
  }
  *(bf16x8*)(xp + (size_t)cell * 128 + coct * 8) = *(bf16x8*)o;
}

// K1: kernel (K,C,3,3) f32 -> wt bf16 [step 36][k 128][c 32]
// step = rs*4+cs ; c = cs*32 + co
__global__ void wtrans_kernel(const float* __restrict__ kin,
                              unsigned short* __restrict__ wt) {
  int e = blockIdx.x * 256 + threadIdx.x;  // 147456 exact
  int co = e & 31;
  int k = (e >> 5) & 127;
  int step = e >> 12;  // 0..35
  int rs = step >> 2;
  int cs = step & 3;
  wt[e] = f2bf(kin[(k * CC + cs * 32 + co) * 9 + rs]);
}

// K2: conv as m97-template GEMM. Grid 448 (16n x 28 h-pairs, XCD-swizzled),
// 256 thr (4 waves). Block tile: M=128 px (2 out-rows x 64 w) x N=128 k.
// K-loop: 36 steps of BK=32c (9 rs x 4 cs). Per step both tiles (A 8KB:
// [128px][32c]; B 8KB: [128k][32c]) staged via global_load_lds (linear,
// width 16), double-buffered; s_waitcnt vmcnt(4) + s_barrier pair (counted
// wait: next step's 4 glds stay in flight). Wave-tile 64x64 = 4x4 frags of
// mfma_f32_16x16x32_bf16. No masks/branches in the K-loop (xp pre-padded).
__global__ __launch_bounds__(256, 2) void conv_kernel(
    const unsigned short* __restrict__ xp, const unsigned short* __restrict__ wt,
    float* __restrict__ out) {
  __shared__ __align__(16) unsigned char xs[2 * 16384];  // 32 KB

  const int tid = threadIdx.x;
  const int lane = tid & 63;
  const int wv = tid >> 6;  // 0..3
  const int wm = wv >> 1;   // M-half
  const int wn = wv & 1;    // N-half

  const int wg = ((blockIdx.x & 7) * 56) + (blockIdx.x >> 3);  // XCD swizzle
  const int n = wg / 28;
  const int hp = wg - n * 28;
  const int h0 = hp * 2;

  const unsigned char* xpb = (const unsigned char*)xp;
  const unsigned char* wtb = (const unsigned char*)wt;

  // per-thread staging offsets
  const int aoff = (tid >> 2) * 256 + (tid & 3) * 16;  // px=(tid>>2), part
  const int laneoff = (lane & 15) * 64 + (lane >> 4) * 16;

  auto issue = [&](int tn) {
    const int rs = tn >> 2;
    const int cs = tn & 3;
    const int fr = (rs * 11) >> 5;  // rs/3
    const int fs = rs - fr * 3;
    const unsigned char* ab =
        xpb + (size_t)((n * 58 + h0 + fr) * 66 + fs) * 256 + cs * 64 + aoff;
    unsigned char* dst = xs + (tn & 1) * 16384 + tid * 16;
    gload_lds16(ab, dst);                   // A, dh=0 (px 0..63)
    gload_lds16(ab + 66 * 256, dst + 4096); // A, dh=1 (px 64..127)
    const unsigned char* bb = wtb + (size_t)tn * 8192 + tid * 16;
    gload_lds16(bb, dst + 8192);            // B, k 0..63
    gload_lds16(bb + 4096, dst + 12288);    // B, k 64..127
  };

  f32x4 acc[4][4] = {};  // [am][bn]

  issue(0);

#pragma unroll 1
  for (int t = 0; t < 36; ++t) {
    if (t < 35) {
      issue(t + 1);
      asm volatile("s_waitcnt vmcnt(4)" ::: "memory");
    } else {
      asm volatile("s_waitcnt vmcnt(0)" ::: "memory");
    }
    __builtin_amdgcn_s_barrier();
    __builtin_amdgcn_sched_barrier(0);

    const unsigned char* buf = xs + (t & 1) * 16384;
    bf16x8 Af[4], Bf[4];
#pragma unroll
    for (int am = 0; am < 4; ++am)
      Af[am] = *(const bf16x8*)(buf + wm * 4096 + am * 1024 + laneoff);
#pragma unroll
    for (int bn = 0; bn < 4; ++bn)
      Bf[bn] = *(const bf16x8*)(buf + 8192 + wn * 4096 + bn * 1024 + laneoff);
#pragma unroll
    for (int am = 0; am < 4; ++am)
#pragma unroll
      for (int bn = 0; bn < 4; ++bn)
        acc[am][bn] = __builtin_amdgcn_mfma_f32_16x16x32_bf16(
            Af[am], Bf[bn], acc[am][bn], 0, 0, 0);

    __builtin_amdgcn_sched_barrier(0);
    __builtin_amdgcn_s_barrier();
  }

  // epilogue: D frag: row(px) = (lane>>4)*4+j, col(k) = lane&15
  const int h = h0 + wm;
#pragma unroll
  for (int am = 0; am < 4; ++am) {
    const int wb = am * 16 + ((lane >> 4) << 2);
#pragma unroll
    for (int bn = 0; bn < 4; ++bn) {
      const int k = wn * 64 + bn * 16 + (lane & 15);
      float* op = out + ((size_t)(n * KK + k) * HH + h) * WW;
#pragma unroll
      for (int j = 0; j < 4; ++j) {
        const int w = wb + j;
        if (w < WW) op[w] = acc[am][bn][j];
      }
    }
  }
}

extern "C" void kernel_launch(void* const* d_in, const int* in_sizes, int n_in,
                              void* d_out, int out_size, void* d_ws, size_t ws_size,
                              hipStream_t stream) {
  const float* x = (const float*)d_in[0];
  const float* kin = (const float*)d_in[1];
  float* out = (float*)d_out;
  unsigned short* wt = (unsigned short*)d_ws;                      // 288 KB
  unsigned short* xp = (unsigned short*)((char*)d_ws + XP_OFF);    // 15.7 MB

  hipLaunchKernelGGL(prepack_kernel, dim3(3828), dim3(256), 0, stream, x, xp);
  hipLaunchKernelGGL(wtrans_kernel, dim3(576), dim3(256), 0, stream, kin, wt);
  hipLaunchKernelGGL(conv_kernel, dim3(448), dim3(256), 0, stream, xp, wt, out);
}

// Round 9
// 40.330 us; speedup vs baseline: 1.5707x; 1.2502x over previous
//
#include <hip/hip_runtime.h>
#include <hip/hip_bf16.h>

typedef __attribute__((ext_vector_type(8))) short bf16x8;
typedef __attribute__((ext_vector_type(4))) float f32x4;

#define CC 128
#define KK 128
#define HH 56
#define WW 56
#define HW (HH * WW)

#define XP_OFF (512 * 1024)  // ws: wt at 0 (288KB), xp at 512KB (15.7MB)

__device__ __forceinline__ unsigned short f2bf(float f) {
  unsigned int u = __builtin_bit_cast(unsigned int, f);
  u += 0x7FFFu + ((u >> 16) & 1u);
  return (unsigned short)(u >> 16);
}

__device__ __forceinline__ void gload_lds16(const void* g, void* l) {
  __builtin_amdgcn_global_load_lds((__attribute__((address_space(1))) void*)g,
                                   (__attribute__((address_space(3))) void*)l,
                                   16, 0, 0);
}

// K0: x fp32 NCHW -> xp bf16 cells[16B]: idx = ((n*58 + h)*16 + cp)*66 + w
// cell = channels cp*8..cp*8+7 at padded (h,w). Halo (h=0,57; w=0,57..65)
// zeroed so conv has NO bounds checks.
__global__ void prepack_kernel(const float* __restrict__ x,
                               unsigned short* __restrict__ xp) {
  int idx = blockIdx.x * 256 + threadIdx.x;  // 979968 exact
  int w = idx % 66;
  int q = idx / 66;
  int cp = q & 15;
  int r = q >> 4;
  int h = r % 58;
  int n = r / 58;
  bool ok = (h >= 1) && (h <= 56) && (w >= 1) && (w <= 56);
  const float* src = x + ((size_t)(n * CC + cp * 8) * HH + (h - 1)) * WW + (w - 1);
  unsigned short o[8];
#pragma unroll
  for (int ci = 0; ci < 8; ++ci) {
    float v = ok ? src[(size_t)ci * HW] : 0.f;
    o[ci] = f2bf(v);
  }
  *(bf16x8*)(xp + (size_t)idx * 8) = *(bf16x8*)o;
}

// K1: kernel (K,C,3,3) f32 -> wt bf16: e = ((step*4 + part)*128 + k)*8 + j
// step = rs*4+cs ; c = cs*32 + part*8 + j  (B-tile part-major for LDS layout)
__global__ void wtrans_kernel(const float* __restrict__ kin,
                              unsigned short* __restrict__ wt) {
  int e = blockIdx.x * 256 + threadIdx.x;  // 147456 exact
  int j = e & 7;
  int k = (e >> 3) & 127;
  int part = (e >> 10) & 3;
  int step = e >> 12;  // 0..35
  int rs = step >> 2;
  int cs = step & 3;
  int c = cs * 32 + part * 8 + j;
  wt[e] = f2bf(kin[(k * CC + c) * 9 + rs]);
}

// K2: conv as GEMM, mfma_f32_16x16x32_bf16. Grid 448 (XCD-swizzled), 256 thr.
// Block: M=128 px (2 rows x 64 w) x N=128 k; 36 K-steps of BK=32c.
// LDS: 3 buffers x 16KB (A [4 cpart][128 px][16B] + B [4 cpart][128 k][16B],
// transposed so b128 frag reads are bank-complete). Staging via
// global_load_lds (linear dest, coalesced src), depth-2 prefetch, counted
// vmcnt(4), ONE barrier per step.
__global__ __launch_bounds__(256, 3) void conv_kernel(
    const unsigned short* __restrict__ xp, const unsigned short* __restrict__ wt,
    float* __restrict__ out) {
  __shared__ __align__(16) unsigned char xs[3 * 16384];  // 48 KB

  const int tid = threadIdx.x;
  const int lane = tid & 63;
  const int wv = tid >> 6;  // 0..3
  const int wm = wv >> 1;   // M-half (out row within pair)
  const int wn = wv & 1;    // N-half

  const int wg = ((blockIdx.x & 7) * 56) + (blockIdx.x >> 3);  // XCD swizzle
  const int n = wg / 28;
  const int hp = wg - n * 28;
  const int h0 = hp * 2;

  const unsigned char* xpb = (const unsigned char*)xp;
  const unsigned char* wtb = (const unsigned char*)wt;

  auto issue = [&](int t, int wr) {
    const int rs = t >> 2;
    const int cs = t & 3;
    const int fr = (rs * 11) >> 5;  // rs/3
    const int fs = rs - fr * 3;
    unsigned char* dst = xs + wr * 16384;
    // A: dh = 0,1 ; LDS [part=wv][px = dh*64 + lane]
    const size_t rowcell = ((size_t)(n * 58 + h0 + fr) * 16 + cs * 4 + wv) * 66 + fs;
    gload_lds16(xpb + (rowcell + lane) * 16, dst + wv * 2048 + lane * 16);
    gload_lds16(xpb + (rowcell + 16 * 66 + lane) * 16,
                dst + wv * 2048 + 1024 + lane * 16);
    // B: k-halves ; LDS [part=wv][k = kc*64 + lane]
    const unsigned char* bs = wtb + (size_t)t * 8192 + wv * 2048 + lane * 16;
    gload_lds16(bs, dst + 8192 + wv * 2048 + lane * 16);
    gload_lds16(bs + 1024, dst + 8192 + wv * 2048 + 1024 + lane * 16);
  };

  issue(0, 0);
  issue(1, 1);

  f32x4 acc[4][4] = {};  // [am][bn]
  const int fo = (lane >> 4) * 2048 + (lane & 15) * 16;  // frag base (part,row)

  int rd = 0, wr = 2;
#pragma unroll 1
  for (int t = 0; t < 36; ++t) {
    if (t < 35)
      asm volatile("s_waitcnt vmcnt(4)" ::: "memory");
    else
      asm volatile("s_waitcnt vmcnt(0)" ::: "memory");
    __builtin_amdgcn_s_barrier();

    if (t < 34) issue(t + 2, wr);

    const unsigned char* buf = xs + rd * 16384;
    bf16x8 Af[4], Bf[4];
#pragma unroll
    for (int am = 0; am < 4; ++am)
      Af[am] = *(const bf16x8*)(buf + fo + (wm * 64 + am * 16) * 16);
#pragma unroll
    for (int bn = 0; bn < 4; ++bn)
      Bf[bn] = *(const bf16x8*)(buf + 8192 + fo + (wn * 64 + bn * 16) * 16);

    __builtin_amdgcn_s_setprio(1);
#pragma unroll
    for (int am = 0; am < 4; ++am)
#pragma unroll
      for (int bn = 0; bn < 4; ++bn)
        acc[am][bn] = __builtin_amdgcn_mfma_f32_16x16x32_bf16(
            Af[am], Bf[bn], acc[am][bn], 0, 0, 0);
    __builtin_amdgcn_s_setprio(0);

    rd = (rd == 2) ? 0 : rd + 1;
    wr = (wr == 2) ? 0 : wr + 1;
  }

  // epilogue: D frag row(px) = (lane>>4)*4 + j, col(k) = lane&15.
  // acc[am][bn] = 4 consecutive w -> one dwordx4 store.
  const int h = h0 + wm;
  const int q4 = (lane >> 4) << 2;
#pragma unroll
  for (int am = 0; am < 4; ++am) {
    const int w0 = am * 16 + q4;
    if (w0 < WW) {
#pragma unroll
      for (int bn = 0; bn < 4; ++bn) {
        const int k = wn * 64 + bn * 16 + (lane & 15);
        float* op = out + ((size_t)(n * KK + k) * HH + h) * WW + w0;
        *(f32x4*)op = acc[am][bn];
      }
    }
  }
}

extern "C" void kernel_launch(void* const* d_in, const int* in_sizes, int n_in,
                              void* d_out, int out_size, void* d_ws, size_t ws_size,
                              hipStream_t stream) {
  const float* x = (const float*)d_in[0];
  const float* kin = (const float*)d_in[1];
  float* out = (float*)d_out;
  unsigned short* wt = (unsigned short*)d_ws;                    // 288 KB
  unsigned short* xp = (unsigned short*)((char*)d_ws + XP_OFF);  // 15.7 MB

  hipLaunchKernelGGL(prepack_kernel, dim3(3828), dim3(256), 0, stream, x, xp);
  hipLaunchKernelGGL(wtrans_kernel, dim3(576), dim3(256), 0, stream, kin, wt);
  hipLaunchKernelGGL(conv_kernel, dim3(448), dim3(256), 0, stream, xp, wt, out);
}